// Round 17
// baseline (80.798 us; speedup 1.0000x reference)
//
#include <hip/hip_runtime.h>
#include <hip/hip_bf16.h>
#include <math.h>

#define ALPHA_ 0.2f
#define N_ 16
#define H_ 32
#define W_ 32
#define T_ 16
#define V_ 64
#define P_ (H_*W_)  // 1024

// Xt padded geometry: 34 rows (h+1), 34 cols (w+1), zero halos.
#define HP_ 34
#define WP_ 34
#define XROW_ (WP_*V_*T_)   // elements per (b,hp) row = 34*1024

typedef __bf16 bf16x8 __attribute__((ext_vector_type(8)));
typedef float  f32x4  __attribute__((ext_vector_type(4)));

static __device__ inline unsigned short bf16bits(float f) {
    __hip_bfloat16 b = __float2bfloat16(f);
    return *reinterpret_cast<unsigned short*>(&b);
}

// ---------------------------------------------------------------------------
// Kernel 0: transpose X[b,h,w,ti,v] f32 -> Xt[b][hp][wp][v][ti] bf16 with
// zero halos. grid = 16*34*4 + 1 = 2177; last block builds Bfrag + adj_norm.
// XCD-matched swizzle (b-pair per XCD). Unchanged from champion.
// ---------------------------------------------------------------------------
__global__ __launch_bounds__(256, 4) void tr2_k(const float* __restrict__ X,
                                                __hip_bfloat16* __restrict__ Xt,
                                                const float* __restrict__ CW,
                                                const float* __restrict__ Bm,
                                                __hip_bfloat16* __restrict__ Bfrag,
                                                float* __restrict__ adjn) {
    int orig = blockIdx.x;
    int tid = threadIdx.x;

    if (orig == N_*34*4) {
        __shared__ float sd[64];
        float row[64];
        int lane = tid;
        if (tid < 64) {
            int t = lane & 15, kg = lane >> 4;
            #pragma unroll
            for (int dw = 0; dw < 3; ++dw) {
                #pragma unroll
                for (int pr = 0; pr < 2; ++pr) {
                    __hip_bfloat16* dst = Bfrag + ((size_t)((dw*2+pr)*64 + lane))*8;
                    #pragma unroll
                    for (int i = 0; i < 8; ++i) {
                        int ti = (kg & 1)*8 + i;
                        float val;
                        if (pr == 0) { int dh = kg >> 1; val = CW[((dh*3+dw)*16+ti)*16 + t]; }
                        else          val = (kg < 2) ? CW[((2*3+dw)*16+ti)*16 + t] : 0.f;
                        dst[i] = __float2bfloat16(val);
                    }
                }
            }
            int i = lane;
            float mn = 1e30f, mx = -1e30f;
            #pragma unroll
            for (int v = 0; v < 64; ++v) {
                float x = Bm[i*64 + v] + (v == i ? 1.f : 0.f);
                row[v] = x;
                mn = fminf(mn, x);
                mx = fmaxf(mx, x);
            }
            #pragma unroll
            for (int off = 32; off > 0; off >>= 1) {
                mn = fminf(mn, __shfl_xor(mn, off));
                mx = fmaxf(mx, __shfl_xor(mx, off));
            }
            float inv = 1.f / (mx - mn);
            float rs = 0.f;
            #pragma unroll
            for (int v = 0; v < 64; ++v) {
                row[v] = (row[v] - mn) * inv;
                rs += row[v];
            }
            sd[i] = rsqrtf(rs);
        }
        __syncthreads();
        if (tid < 64) {
            float d = sd[tid];
            #pragma unroll
            for (int v = 0; v < 64; ++v) adjn[tid*64 + v] = row[v] * d * sd[v];
        }
        return;
    }

    // XCD-matched swizzle: XCD x = orig&7 gets bids [x*272, (x+1)*272) = b pair.
    int bid = (orig & 7) * 272 + (orig >> 3);
    int b   = bid / 136;
    int r   = bid % 136;
    int hp  = r >> 2;
    int wq  = r & 3;              // 8-w chunk

    __hip_bfloat16* rowbase = Xt + ((size_t)b*HP_ + hp) * XROW_;
    __hip_bfloat16* dst = rowbase + (size_t)(wq*8 + 1) * (V_*T_);

    // extra w-halo column (every hp row)
    if (wq == 0) {   // wp = 0
        uint4 z = {0u,0u,0u,0u};
        if (tid < 128) ((uint4*)rowbase)[tid] = z;
    } else if (wq == 3) {  // wp = 33
        uint4 z = {0u,0u,0u,0u};
        if (tid < 128) ((uint4*)(rowbase + (size_t)33*(V_*T_)))[tid] = z;
    }

    if (hp == 0 || hp == 33) {    // zero halo row chunk: 16 KB
        uint4 z = {0u,0u,0u,0u};
        uint4* d = (uint4*)dst;
        #pragma unroll
        for (int k = 0; k < 4; ++k) d[tid + 256*k] = z;
        return;
    }
    int h = hp - 1;

    __shared__ __align__(16) unsigned sx[4096];  // 16 KB

    int vq  = tid & 15;
    int tp4 = (tid >> 4) & 3;
    int w4  = tid >> 6;           // 0..3
    const float* Xb = X + (((size_t)(b*H_ + h)*W_ + wq*8) * T_) * V_ + vq*4;

    f32x4 xr[2][2][2];            // [iw][th][tk]
    #pragma unroll
    for (int iw = 0; iw < 2; ++iw) {
        int wl = iw*4 + w4;
        #pragma unroll
        for (int th = 0; th < 2; ++th) {
            #pragma unroll
            for (int tk = 0; tk < 2; ++tk) {
                int ti = (th*4 + tp4)*2 + tk;
                xr[iw][th][tk] = *(const f32x4*)(Xb + ((size_t)wl*T_ + ti)*V_);
            }
        }
    }
    #pragma unroll
    for (int iw = 0; iw < 2; ++iw) {
        int wl = iw*4 + w4;
        #pragma unroll
        for (int th = 0; th < 2; ++th) {
            int tp = th*4 + tp4;
            uint4 pk;
            unsigned* pw = (unsigned*)&pk;
            #pragma unroll
            for (int k2 = 0; k2 < 4; ++k2)
                pw[k2] = (unsigned)bf16bits(xr[iw][th][0][k2])
                       | ((unsigned)bf16bits(xr[iw][th][1][k2]) << 16);
            *(uint4*)&sx[(wl*8 + tp)*64 + (vq ^ tp4)*4] = pk;
        }
    }
    __syncthreads();

    #pragma unroll
    for (int k = 0; k < 4; ++k) {
        int c   = tid + 256*k;
        int wl  = c >> 7;
        int vv  = (c >> 1) & 63;
        int thf = c & 1;
        uint4 o;
        unsigned* ow = (unsigned*)&o;
        #pragma unroll
        for (int q = 0; q < 4; ++q)
            ow[q] = sx[(wl*8 + thf*4 + q)*64 + ((vv >> 2) ^ q)*4 + (vv & 3)];
        *(uint4*)(dst + ((size_t)wl*V_ + vv)*T_ + thf*8) = o;
    }
}

// ---------------------------------------------------------------------------
// Kernel 1: conv via MFMA (branch-free A-loads from w-padded Xt) + Ei/Ej.
// grid = 2048 (b-pair per XCD, reversed within XCD). Unchanged from champion.
// ---------------------------------------------------------------------------
__global__ __launch_bounds__(256, 3) void conv_k(const __hip_bfloat16* __restrict__ Xt,
                                                 const __hip_bfloat16* __restrict__ Bfrag,
                                                 const float* __restrict__ CB,
                                                 const float* __restrict__ av,
                                                 __hip_bfloat16* __restrict__ Whb,
                                                 float* __restrict__ Eihi,
                                                 float* __restrict__ Eihj) {
    __shared__ float sEi[4][16], sEj[4][16];

    int orig = blockIdx.x;
    int bi   = (orig & 7) * 256 + (255 - (orig >> 3));   // reversed within XCD
    int b    = bi >> 7;
    int rem  = bi & 127;
    int h    = rem >> 2;
    int vg   = rem & 3, vb = vg * 16;

    int tid = threadIdx.x, lane = tid & 63, wc = tid >> 6;
    int lm = lane & 15, kg = lane >> 4;

    bf16x8 Bf01[3], Bf2[3];
    #pragma unroll
    for (int dw = 0; dw < 3; ++dw) {
        Bf01[dw] = *(const bf16x8*)(Bfrag + (size_t)((dw*2+0)*64 + lane)*8);
        Bf2 [dw] = *(const bf16x8*)(Bfrag + (size_t)((dw*2+1)*64 + lane)*8);
    }
    float cb = CB[lm];
    f32x4 acc[8];
    #pragma unroll
    for (int wi = 0; wi < 8; ++wi) acc[wi] = (f32x4){cb, cb, cb, cb};

    const __hip_bfloat16* base01 =
        Xt + ((size_t)(b*HP_ + h + (kg>>1)))*XROW_
           + (size_t)(wc*8)*(V_*T_) + (vb + lm)*T_ + (kg&1)*8;
    const __hip_bfloat16* base2  =
        Xt + ((size_t)(b*HP_ + h + 2))*XROW_
           + (size_t)(wc*8)*(V_*T_) + (vb + lm)*T_ + (kg&1)*8;

    bf16x8 f01[10], f2[10];
    #pragma unroll
    for (int u = 0; u < 10; ++u) {
        f01[u] = *(const bf16x8*)(base01 + (size_t)u*(V_*T_));
        f2 [u] = *(const bf16x8*)(base2  + (size_t)u*(V_*T_));
    }

    #pragma unroll
    for (int u = 0; u < 10; ++u) {
        #pragma unroll
        for (int dw = 0; dw < 3; ++dw) {
            int wi = u - dw;                       // compile-time
            if (wi >= 0 && wi < 8) {
                acc[wi] = __builtin_amdgcn_mfma_f32_16x16x32_bf16(f01[u], Bf01[dw], acc[wi], 0, 0, 0);
                acc[wi] = __builtin_amdgcn_mfma_f32_16x16x32_bf16(f2 [u], Bf2 [dw], acc[wi], 0, 0, 0);
            }
        }
    }

    // ---- fused Ei/Ej partials (lane holds t=lm, v=vb+kg*4+r) ----
    float si[4] = {0.f,0.f,0.f,0.f}, sj[4] = {0.f,0.f,0.f,0.f};
    {
        const float* avb = av + (h & 1)*1024 + wc*8*16 + lm;
        #pragma unroll
        for (int wi = 0; wi < 8; ++wi) {
            float ai = avb[wi*16];
            float aj = avb[wi*16 + 512];
            #pragma unroll
            for (int r = 0; r < 4; ++r) {
                si[r] += acc[wi][r] * ai;
                sj[r] += acc[wi][r] * aj;
            }
        }
        #pragma unroll
        for (int off = 1; off < 16; off <<= 1) {
            #pragma unroll
            for (int r = 0; r < 4; ++r) {
                si[r] += __shfl_xor(si[r], off);
                sj[r] += __shfl_xor(sj[r], off);
            }
        }
    }
    if (lm == 0) {
        #pragma unroll
        for (int r = 0; r < 4; ++r) {
            sEi[wc][kg*4 + r] = si[r];
            sEj[wc][kg*4 + r] = sj[r];
        }
    }

    // ---- Whb store: col = lm = t, rows v = vb + kg*4 + r ----
    #pragma unroll
    for (int wi = 0; wi < 8; ++wi) {
        int p = h*W_ + wc*8 + wi;
        unsigned short u0 = bf16bits(acc[wi][0]);
        unsigned short u1 = bf16bits(acc[wi][1]);
        unsigned short u2 = bf16bits(acc[wi][2]);
        unsigned short u3 = bf16bits(acc[wi][3]);
        uint2 pk;
        pk.x = (unsigned)u0 | ((unsigned)u1 << 16);
        pk.y = (unsigned)u2 | ((unsigned)u3 << 16);
        *(uint2*)(Whb + ((size_t)(b*T_ + lm)*P_ + p)*V_ + vb + kg*4) = pk;
    }

    __syncthreads();
    if (tid < 16) {
        float a = sEi[0][tid] + sEi[1][tid] + sEi[2][tid] + sEi[3][tid];
        float c = sEj[0][tid] + sEj[1][tid] + sEj[2][tid] + sEj[3][tid];
        Eihi[((size_t)b*H_ + h)*V_ + vb + tid] = a;
        Eihj[((size_t)b*H_ + h)*V_ + vb + tid] = c;
    }
}

// ---------------------------------------------------------------------------
// Kernel 2 (REWRITTEN): att + Mt, one block per (b,t). grid = 256, XCD-
// swizzled to match out_k's b-mapping. Softmax recomputed per t (identical
// values/order -> bit-identical Mt). Phase 2 writes Mt[b,t,v,j] as uint4:
// wave instruction = 1 KB contiguous (vs old 2B scattered @128B stride from
// cross-XCD blocks -> partial-line RMW).
// ---------------------------------------------------------------------------
__global__ __launch_bounds__(256, 2) void att_m2_k(const float* __restrict__ Eihi,
                                                   const float* __restrict__ Eihj,
                                                   const float* __restrict__ adjn,
                                                   __hip_bfloat16* __restrict__ Mt) {
    int orig = blockIdx.x;
    int bi   = (orig & 7) * 32 + (orig >> 3);   // b-pair per XCD
    int b = bi >> 4;
    int t = bi & 15;
    int tid = threadIdx.x;

    __shared__ float sEi[16][64];    // [tp][i]
    __shared__ float sEj[16][64];    // [tp][j]
    __shared__ float s_att[64][65];  // [i][j], padded
    __shared__ float sadj[64][64];   // [i][v]

    // ---- stage Ei/Ej (h-pair summed) and adjn ----
    const float* ebi = Eihi + (size_t)b*H_*V_;
    const float* ebj = Eihj + (size_t)b*H_*V_;
    #pragma unroll
    for (int k = 0; k < 4; ++k) {
        int idx = tid + 256*k;            // 1024 = 16 tp x 64 i
        int i  = idx & 63;
        int tp = idx >> 6;
        sEi[tp][i] = ebi[(2*tp)*V_ + i] + ebi[(2*tp+1)*V_ + i];
        sEj[tp][i] = ebj[(2*tp)*V_ + i] + ebj[(2*tp+1)*V_ + i];
    }
    #pragma unroll
    for (int k = 0; k < 16; ++k) {
        int idx = tid + 256*k;            // 4096
        sadj[idx >> 6][idx & 63] = adjn[idx];
    }
    __syncthreads();

    // ---- phase 1: softmax -> s_att[i][j] (att at this block's t) ----
    {
        int i1 = tid >> 2;                // 0..63
        int jq = tid & 3;
        float ei[16];
        #pragma unroll
        for (int tp = 0; tp < 16; ++tp) ei[tp] = sEi[tp][i1];
        #pragma unroll 2
        for (int jj = 0; jj < 16; ++jj) {
            int j = jq*16 + jj;
            float e[16];
            float mxe = -1e30f;
            #pragma unroll
            for (int tp = 0; tp < 16; ++tp) {
                float x = ei[tp] + sEj[tp][j];
                x = (x >= 0.f) ? x : ALPHA_ * x;
                e[tp] = x;
                mxe = fmaxf(mxe, x);
            }
            float s = 0.f;
            float evt = 0.f;
            #pragma unroll
            for (int tp = 0; tp < 16; ++tp) {
                float ex = __expf(e[tp] - mxe);
                s += ex;
                if (tp == t) evt = ex;
            }
            s_att[i1][j] = evt * (1.f / s);
        }
    }
    __syncthreads();

    // ---- phase 2: M[j,v] = sum_i att[i][j] * adjn[i][v]; coalesced writes --
    int jo = tid & 7;                     // 8 j's of 8
    int v0 = tid >> 3;                    // 0..31
    #pragma unroll
    for (int pass = 0; pass < 2; ++pass) {
        int v = v0 + pass*32;
        float acc[8] = {0.f,0.f,0.f,0.f,0.f,0.f,0.f,0.f};
        for (int i = 0; i < 64; ++i) {
            float an = sadj[i][v];
            const float* sa = &s_att[i][jo*8];
            #pragma unroll
            for (int q = 0; q < 8; ++q) acc[q] += sa[q] * an;
        }
        uint4 pk;
        unsigned* pw = (unsigned*)&pk;
        #pragma unroll
        for (int q2 = 0; q2 < 4; ++q2)
            pw[q2] = (unsigned)bf16bits(acc[2*q2])
                   | ((unsigned)bf16bits(acc[2*q2+1]) << 16);
        *(uint4*)(Mt + ((size_t)(b*T_ + t)*V_ + v)*V_ + jo*8) = pk;
    }
}

// ---------------------------------------------------------------------------
// Kernel 3 (MFMA): out[b,p,t,v] = elu( sum_j Whb[b,t,p,j] * Mt[b,t,v,j] ).
// Swapped operand roles (A = Mt -> D rows are v -> f32x4 plain stores).
// Unchanged from r16.
// ---------------------------------------------------------------------------
__global__ __launch_bounds__(256, 6) void out_k(const __hip_bfloat16* __restrict__ Whb,
                                                const __hip_bfloat16* __restrict__ Mt,
                                                float* __restrict__ out) {
    int orig = blockIdx.x;
    int bi   = (orig & 7) * 256 + (orig >> 3);   // 8 XCDs x 256 contiguous
    int pc = bi & 7;
    int t  = (bi >> 3) & 15;
    int b  = bi >> 7;

    int tid  = threadIdx.x;
    int lane = tid & 63;
    int wid  = tid >> 6;
    int lm   = lane & 15;
    int lk   = lane >> 4;

    const __hip_bfloat16* Ab = Whb + ((size_t)(b*T_ + t)*P_ + pc*128) * V_;
    const __hip_bfloat16* Bb = Mt  + (size_t)(b*T_ + t) * (V_*V_);

    f32x4 acc[2][4];
    #pragma unroll
    for (int pt = 0; pt < 2; ++pt)
        #pragma unroll
        for (int vt = 0; vt < 4; ++vt) acc[pt][vt] = (f32x4){0.f,0.f,0.f,0.f};

    #pragma unroll
    for (int kf = 0; kf < 2; ++kf) {
        int ko = kf*32 + lk*8;
        // B-operand (n = p): Whb rows p, j contiguous
        bf16x8 b0 = *(const bf16x8*)(Ab + ((size_t)((wid*2+0)*16 + lm))*V_ + ko);
        bf16x8 b1 = *(const bf16x8*)(Ab + ((size_t)((wid*2+1)*16 + lm))*V_ + ko);
        #pragma unroll
        for (int vt = 0; vt < 4; ++vt) {
            // A-operand (m = v): Mt rows v, j contiguous
            bf16x8 a = *(const bf16x8*)(Bb + ((size_t)(vt*16 + lm))*V_ + ko);
            acc[0][vt] = __builtin_amdgcn_mfma_f32_16x16x32_bf16(a, b0, acc[0][vt], 0, 0, 0);
            acc[1][vt] = __builtin_amdgcn_mfma_f32_16x16x32_bf16(a, b1, acc[1][vt], 0, 0, 0);
        }
    }

    // D: col = lm = p-offset, rows = v = vt*16 + lk*4 + r  -> f32x4 in v
    #pragma unroll
    for (int pt = 0; pt < 2; ++pt) {
        int p = pc*128 + (wid*2 + pt)*16 + lm;
        float* op = out + ((size_t)(b*P_ + p)*T_ + t)*V_;
        #pragma unroll
        for (int vt = 0; vt < 4; ++vt) {
            f32x4 e;
            #pragma unroll
            for (int r = 0; r < 4; ++r) {
                float x = acc[pt][vt][r];
                e[r] = (x > 0.f) ? x : (__expf(x) - 1.f);
            }
            *(f32x4*)(op + vt*16 + lk*4) = e;
        }
    }
}

// ---------------------------------------------------------------------------
extern "C" void kernel_launch(void* const* d_in, const int* in_sizes, int n_in,
                              void* d_out, int out_size, void* d_ws, size_t ws_size,
                              hipStream_t stream) {
    const float* X  = (const float*)d_in[0];  // h: (16,32,32,16,64)
    const float* CW = (const float*)d_in[1];  // conv_w: (3,3,16,16)
    const float* CB = (const float*)d_in[2];  // conv_b: (16,)
    const float* av = (const float*)d_in[3];  // a: (2048,1)
    const float* Bm = (const float*)d_in[4];  // B: (64,64)
    float* outp = (float*)d_out;

    // ws: Whb (33.55MB) | Mt (2MB) | Eihi | Eihj | adjn | Bfrag
    __hip_bfloat16* Whb = (__hip_bfloat16*)d_ws;
    __hip_bfloat16* Mt  = Whb + (size_t)N_*T_*P_*V_;
    float* Eihi = (float*)(Mt + (size_t)N_*T_*V_*V_);   // 16*32*64
    float* Eihj = Eihi + (size_t)N_*H_*V_;
    float* adjn = Eihj + (size_t)N_*H_*V_;
    __hip_bfloat16* Bfrag = (__hip_bfloat16*)(adjn + V_*V_);

    // Xt scratch (37.9MB, h+w padded) lives in d_out; out_k overwrites it.
    __hip_bfloat16* Xt = (__hip_bfloat16*)d_out;

    tr2_k   <<<N_*34*4 + 1, 256, 0, stream>>>(X, Xt, CW, Bm, Bfrag, adjn);
    conv_k  <<<2048,        256, 0, stream>>>(Xt, Bfrag, CB, av, Whb, Eihi, Eihj);
    att_m2_k<<<N_*T_,       256, 0, stream>>>(Eihi, Eihj, adjn, Mt);
    out_k   <<<N_*T_*8,     256, 0, stream>>>(Whb, Mt, outp);
}

// Round 18
// 75.065 us; speedup vs baseline: 1.0764x; 1.0764x over previous
//
#include <hip/hip_runtime.h>
#include <hip/hip_bf16.h>
#include <math.h>

#define ALPHA_ 0.2f
#define N_ 16
#define H_ 32
#define W_ 32
#define T_ 16
#define V_ 64
#define P_ (H_*W_)  // 1024

// Xt padded geometry: 34 rows (h+1), 34 cols (w+1), zero halos.
#define HP_ 34
#define WP_ 34
#define XROW_ (WP_*V_*T_)   // elements per (b,hp) row = 34*1024

typedef __bf16 bf16x8 __attribute__((ext_vector_type(8)));
typedef float  f32x4  __attribute__((ext_vector_type(4)));

static __device__ inline unsigned short bf16bits(float f) {
    __hip_bfloat16 b = __float2bfloat16(f);
    return *reinterpret_cast<unsigned short*>(&b);
}

// ---------------------------------------------------------------------------
// Kernel 0: transpose X[b,h,w,ti,v] f32 -> Xt[b][hp][wp][v][ti] bf16 with
// zero halos. grid = 16*34*4 + 1 = 2177; last block builds Bfrag + adj_norm.
// XCD-matched swizzle (b-pair per XCD) so conv's Xt reads hit producer L2.
// ---------------------------------------------------------------------------
__global__ __launch_bounds__(256, 4) void tr2_k(const float* __restrict__ X,
                                                __hip_bfloat16* __restrict__ Xt,
                                                const float* __restrict__ CW,
                                                const float* __restrict__ Bm,
                                                __hip_bfloat16* __restrict__ Bfrag,
                                                float* __restrict__ adjn) {
    int orig = blockIdx.x;
    int tid = threadIdx.x;

    if (orig == N_*34*4) {
        __shared__ float sd[64];
        float row[64];
        int lane = tid;
        if (tid < 64) {
            int t = lane & 15, kg = lane >> 4;
            #pragma unroll
            for (int dw = 0; dw < 3; ++dw) {
                #pragma unroll
                for (int pr = 0; pr < 2; ++pr) {
                    __hip_bfloat16* dst = Bfrag + ((size_t)((dw*2+pr)*64 + lane))*8;
                    #pragma unroll
                    for (int i = 0; i < 8; ++i) {
                        int ti = (kg & 1)*8 + i;
                        float val;
                        if (pr == 0) { int dh = kg >> 1; val = CW[((dh*3+dw)*16+ti)*16 + t]; }
                        else          val = (kg < 2) ? CW[((2*3+dw)*16+ti)*16 + t] : 0.f;
                        dst[i] = __float2bfloat16(val);
                    }
                }
            }
            int i = lane;
            float mn = 1e30f, mx = -1e30f;
            #pragma unroll
            for (int v = 0; v < 64; ++v) {
                float x = Bm[i*64 + v] + (v == i ? 1.f : 0.f);
                row[v] = x;
                mn = fminf(mn, x);
                mx = fmaxf(mx, x);
            }
            #pragma unroll
            for (int off = 32; off > 0; off >>= 1) {
                mn = fminf(mn, __shfl_xor(mn, off));
                mx = fmaxf(mx, __shfl_xor(mx, off));
            }
            float inv = 1.f / (mx - mn);
            float rs = 0.f;
            #pragma unroll
            for (int v = 0; v < 64; ++v) {
                row[v] = (row[v] - mn) * inv;
                rs += row[v];
            }
            sd[i] = rsqrtf(rs);
        }
        __syncthreads();
        if (tid < 64) {
            float d = sd[tid];
            #pragma unroll
            for (int v = 0; v < 64; ++v) adjn[tid*64 + v] = row[v] * d * sd[v];
        }
        return;
    }

    // XCD-matched swizzle: XCD x = orig&7 gets bids [x*272, (x+1)*272) = b pair.
    int bid = (orig & 7) * 272 + (orig >> 3);
    int b   = bid / 136;
    int r   = bid % 136;
    int hp  = r >> 2;
    int wq  = r & 3;              // 8-w chunk

    __hip_bfloat16* rowbase = Xt + ((size_t)b*HP_ + hp) * XROW_;
    __hip_bfloat16* dst = rowbase + (size_t)(wq*8 + 1) * (V_*T_);

    // extra w-halo column (every hp row)
    if (wq == 0) {   // wp = 0
        uint4 z = {0u,0u,0u,0u};
        if (tid < 128) ((uint4*)rowbase)[tid] = z;
    } else if (wq == 3) {  // wp = 33
        uint4 z = {0u,0u,0u,0u};
        if (tid < 128) ((uint4*)(rowbase + (size_t)33*(V_*T_)))[tid] = z;
    }

    if (hp == 0 || hp == 33) {    // zero halo row chunk: 16 KB
        uint4 z = {0u,0u,0u,0u};
        uint4* d = (uint4*)dst;
        #pragma unroll
        for (int k = 0; k < 4; ++k) d[tid + 256*k] = z;
        return;
    }
    int h = hp - 1;

    __shared__ __align__(16) unsigned sx[4096];  // 16 KB

    int vq  = tid & 15;
    int tp4 = (tid >> 4) & 3;
    int w4  = tid >> 6;           // 0..3
    const float* Xb = X + (((size_t)(b*H_ + h)*W_ + wq*8) * T_) * V_ + vq*4;

    f32x4 xr[2][2][2];            // [iw][th][tk]
    #pragma unroll
    for (int iw = 0; iw < 2; ++iw) {
        int wl = iw*4 + w4;
        #pragma unroll
        for (int th = 0; th < 2; ++th) {
            #pragma unroll
            for (int tk = 0; tk < 2; ++tk) {
                int ti = (th*4 + tp4)*2 + tk;
                xr[iw][th][tk] = *(const f32x4*)(Xb + ((size_t)wl*T_ + ti)*V_);
            }
        }
    }
    #pragma unroll
    for (int iw = 0; iw < 2; ++iw) {
        int wl = iw*4 + w4;
        #pragma unroll
        for (int th = 0; th < 2; ++th) {
            int tp = th*4 + tp4;
            uint4 pk;
            unsigned* pw = (unsigned*)&pk;
            #pragma unroll
            for (int k2 = 0; k2 < 4; ++k2)
                pw[k2] = (unsigned)bf16bits(xr[iw][th][0][k2])
                       | ((unsigned)bf16bits(xr[iw][th][1][k2]) << 16);
            *(uint4*)&sx[(wl*8 + tp)*64 + (vq ^ tp4)*4] = pk;
        }
    }
    __syncthreads();

    #pragma unroll
    for (int k = 0; k < 4; ++k) {
        int c   = tid + 256*k;
        int wl  = c >> 7;
        int vv  = (c >> 1) & 63;
        int thf = c & 1;
        uint4 o;
        unsigned* ow = (unsigned*)&o;
        #pragma unroll
        for (int q = 0; q < 4; ++q)
            ow[q] = sx[(wl*8 + thf*4 + q)*64 + ((vv >> 2) ^ q)*4 + (vv & 3)];
        *(uint4*)(dst + ((size_t)wl*V_ + vv)*T_ + thf*8) = o;
    }
}

// ---------------------------------------------------------------------------
// Kernel 1: conv via MFMA (branch-free A-loads from w-padded Xt) + Ei/Ej.
// grid = 2048 (b-pair per XCD, reversed within XCD for LRU-friendly reuse
// of tr2's freshest lines).
// ---------------------------------------------------------------------------
__global__ __launch_bounds__(256, 3) void conv_k(const __hip_bfloat16* __restrict__ Xt,
                                                 const __hip_bfloat16* __restrict__ Bfrag,
                                                 const float* __restrict__ CB,
                                                 const float* __restrict__ av,
                                                 __hip_bfloat16* __restrict__ Whb,
                                                 float* __restrict__ Eihi,
                                                 float* __restrict__ Eihj) {
    __shared__ float sEi[4][16], sEj[4][16];

    int orig = blockIdx.x;
    int bi   = (orig & 7) * 256 + (255 - (orig >> 3));   // reversed within XCD
    int b    = bi >> 7;
    int rem  = bi & 127;
    int h    = rem >> 2;
    int vg   = rem & 3, vb = vg * 16;

    int tid = threadIdx.x, lane = tid & 63, wc = tid >> 6;
    int lm = lane & 15, kg = lane >> 4;

    bf16x8 Bf01[3], Bf2[3];
    #pragma unroll
    for (int dw = 0; dw < 3; ++dw) {
        Bf01[dw] = *(const bf16x8*)(Bfrag + (size_t)((dw*2+0)*64 + lane)*8);
        Bf2 [dw] = *(const bf16x8*)(Bfrag + (size_t)((dw*2+1)*64 + lane)*8);
    }
    float cb = CB[lm];
    f32x4 acc[8];
    #pragma unroll
    for (int wi = 0; wi < 8; ++wi) acc[wi] = (f32x4){cb, cb, cb, cb};

    const __hip_bfloat16* base01 =
        Xt + ((size_t)(b*HP_ + h + (kg>>1)))*XROW_
           + (size_t)(wc*8)*(V_*T_) + (vb + lm)*T_ + (kg&1)*8;
    const __hip_bfloat16* base2  =
        Xt + ((size_t)(b*HP_ + h + 2))*XROW_
           + (size_t)(wc*8)*(V_*T_) + (vb + lm)*T_ + (kg&1)*8;

    bf16x8 f01[10], f2[10];
    #pragma unroll
    for (int u = 0; u < 10; ++u) {
        f01[u] = *(const bf16x8*)(base01 + (size_t)u*(V_*T_));
        f2 [u] = *(const bf16x8*)(base2  + (size_t)u*(V_*T_));
    }

    #pragma unroll
    for (int u = 0; u < 10; ++u) {
        #pragma unroll
        for (int dw = 0; dw < 3; ++dw) {
            int wi = u - dw;                       // compile-time
            if (wi >= 0 && wi < 8) {
                acc[wi] = __builtin_amdgcn_mfma_f32_16x16x32_bf16(f01[u], Bf01[dw], acc[wi], 0, 0, 0);
                acc[wi] = __builtin_amdgcn_mfma_f32_16x16x32_bf16(f2 [u], Bf2 [dw], acc[wi], 0, 0, 0);
            }
        }
    }

    // ---- fused Ei/Ej partials (lane holds t=lm, v=vb+kg*4+r) ----
    float si[4] = {0.f,0.f,0.f,0.f}, sj[4] = {0.f,0.f,0.f,0.f};
    {
        const float* avb = av + (h & 1)*1024 + wc*8*16 + lm;
        #pragma unroll
        for (int wi = 0; wi < 8; ++wi) {
            float ai = avb[wi*16];
            float aj = avb[wi*16 + 512];
            #pragma unroll
            for (int r = 0; r < 4; ++r) {
                si[r] += acc[wi][r] * ai;
                sj[r] += acc[wi][r] * aj;
            }
        }
        #pragma unroll
        for (int off = 1; off < 16; off <<= 1) {
            #pragma unroll
            for (int r = 0; r < 4; ++r) {
                si[r] += __shfl_xor(si[r], off);
                sj[r] += __shfl_xor(sj[r], off);
            }
        }
    }
    if (lm == 0) {
        #pragma unroll
        for (int r = 0; r < 4; ++r) {
            sEi[wc][kg*4 + r] = si[r];
            sEj[wc][kg*4 + r] = sj[r];
        }
    }

    // ---- Whb store: col = lm = t, rows v = vb + kg*4 + r ----
    #pragma unroll
    for (int wi = 0; wi < 8; ++wi) {
        int p = h*W_ + wc*8 + wi;
        unsigned short u0 = bf16bits(acc[wi][0]);
        unsigned short u1 = bf16bits(acc[wi][1]);
        unsigned short u2 = bf16bits(acc[wi][2]);
        unsigned short u3 = bf16bits(acc[wi][3]);
        uint2 pk;
        pk.x = (unsigned)u0 | ((unsigned)u1 << 16);
        pk.y = (unsigned)u2 | ((unsigned)u3 << 16);
        *(uint2*)(Whb + ((size_t)(b*T_ + lm)*P_ + p)*V_ + vb + kg*4) = pk;
    }

    __syncthreads();
    if (tid < 16) {
        float a = sEi[0][tid] + sEi[1][tid] + sEi[2][tid] + sEi[3][tid];
        float c = sEj[0][tid] + sEj[1][tid] + sEj[2][tid] + sEj[3][tid];
        Eihi[((size_t)b*H_ + h)*V_ + vb + tid] = a;
        Eihj[((size_t)b*H_ + h)*V_ + vb + tid] = c;
    }
}

// ---------------------------------------------------------------------------
// Kernel 2: att + Mt (precomputed adjn, staged to LDS once).
// grid = N*V (1024), one (b,j) per block, block 256.
// ---------------------------------------------------------------------------
__global__ __launch_bounds__(256, 4) void att_m_k(const float* __restrict__ Eihi,
                                                  const float* __restrict__ Eihj,
                                                  const float* __restrict__ adjn,
                                                  __hip_bfloat16* __restrict__ Mt) {
    int b = blockIdx.x >> 6;
    int j = blockIdx.x & 63;
    int tid = threadIdx.x;
    __shared__ float s_att[64][16];
    __shared__ float sadj[4096];

    #pragma unroll
    for (int k = 0; k < 16; ++k) sadj[tid + 256*k] = adjn[tid + 256*k];

    if (tid < 64) {
        int i = tid;
        const float* ebi = Eihi + (size_t)b*H_*V_;
        const float* ebj = Eihj + (size_t)b*H_*V_;
        float ev[16];
        float mxe = -1e30f;
        #pragma unroll
        for (int t = 0; t < 16; ++t) {
            float x = ebi[(2*t)*V_ + i] + ebi[(2*t+1)*V_ + i]
                    + ebj[(2*t)*V_ + j] + ebj[(2*t+1)*V_ + j];
            x = (x >= 0.f) ? x : ALPHA_ * x;
            ev[t] = x;
            mxe = fmaxf(mxe, x);
        }
        float s = 0.f;
        #pragma unroll
        for (int t = 0; t < 16; ++t) {
            ev[t] = __expf(ev[t] - mxe);
            s += ev[t];
        }
        float invs = 1.f / s;
        #pragma unroll
        for (int t = 0; t < 16; ++t) s_att[i][t] = ev[t] * invs;
    }
    __syncthreads();

    int v = tid & 63, tq = tid >> 6;
    float acc[4] = {0.f, 0.f, 0.f, 0.f};
    for (int i = 0; i < 64; ++i) {
        float an = sadj[i*64 + v];
        #pragma unroll
        for (int u = 0; u < 4; ++u) acc[u] += s_att[i][tq*4 + u] * an;
    }
    #pragma unroll
    for (int u = 0; u < 4; ++u) {
        int t = tq*4 + u;
        Mt[(((size_t)b*T_ + t)*V_ + v)*V_ + j] = __float2bfloat16(acc[u]);
    }
}

// ---------------------------------------------------------------------------
// Kernel 3 (MFMA): out[b,p,t,v] = elu( sum_j Whb[b,t,p,j] * Mt[b,t,v,j] ).
// XCD swizzle matching conv's Whb writes; __launch_bounds__(256,6).
// ---------------------------------------------------------------------------
__global__ __launch_bounds__(256, 6) void out_k(const __hip_bfloat16* __restrict__ Whb,
                                                const __hip_bfloat16* __restrict__ Mt,
                                                float* __restrict__ out) {
    int orig = blockIdx.x;
    int bi   = (orig & 7) * 256 + (orig >> 3);   // 8 XCDs x 256 contiguous
    int pc = bi & 7;
    int t  = (bi >> 3) & 15;
    int b  = bi >> 7;

    int tid  = threadIdx.x;
    int lane = tid & 63;
    int wid  = tid >> 6;
    int lm   = lane & 15;
    int lk   = lane >> 4;

    const __hip_bfloat16* Ab = Whb + ((size_t)(b*T_ + t)*P_ + pc*128) * V_;
    const __hip_bfloat16* Bb = Mt  + (size_t)(b*T_ + t) * (V_*V_);

    f32x4 acc[2][4];
    #pragma unroll
    for (int pt = 0; pt < 2; ++pt)
        #pragma unroll
        for (int vt = 0; vt < 4; ++vt) acc[pt][vt] = (f32x4){0.f,0.f,0.f,0.f};

    #pragma unroll
    for (int kf = 0; kf < 2; ++kf) {
        int ko = kf*32 + lk*8;
        bf16x8 a0 = *(const bf16x8*)(Ab + ((size_t)((wid*2+0)*16 + lm))*V_ + ko);
        bf16x8 a1 = *(const bf16x8*)(Ab + ((size_t)((wid*2+1)*16 + lm))*V_ + ko);
        #pragma unroll
        for (int vt = 0; vt < 4; ++vt) {
            bf16x8 bf = *(const bf16x8*)(Bb + ((size_t)(vt*16 + lm))*V_ + ko);
            acc[0][vt] = __builtin_amdgcn_mfma_f32_16x16x32_bf16(a0, bf, acc[0][vt], 0, 0, 0);
            acc[1][vt] = __builtin_amdgcn_mfma_f32_16x16x32_bf16(a1, bf, acc[1][vt], 0, 0, 0);
        }
    }

    #pragma unroll
    for (int pt = 0; pt < 2; ++pt) {
        #pragma unroll
        for (int vt = 0; vt < 4; ++vt) {
            #pragma unroll
            for (int r = 0; r < 4; ++r) {
                int p  = pc*128 + (wid*2 + pt)*16 + lk*4 + r;
                int vv = vt*16 + lm;
                float x = acc[pt][vt][r];
                x = (x > 0.f) ? x : (__expf(x) - 1.f);
                out[((size_t)(b*P_ + p)*T_ + t)*V_ + vv] = x;
            }
        }
    }
}

// ---------------------------------------------------------------------------
extern "C" void kernel_launch(void* const* d_in, const int* in_sizes, int n_in,
                              void* d_out, int out_size, void* d_ws, size_t ws_size,
                              hipStream_t stream) {
    const float* X  = (const float*)d_in[0];  // h: (16,32,32,16,64)
    const float* CW = (const float*)d_in[1];  // conv_w: (3,3,16,16)
    const float* CB = (const float*)d_in[2];  // conv_b: (16,)
    const float* av = (const float*)d_in[3];  // a: (2048,1)
    const float* Bm = (const float*)d_in[4];  // B: (64,64)
    float* outp = (float*)d_out;

    // ws: Whb (33.55MB) | Mt (2MB) | Eihi | Eihj | adjn | Bfrag
    __hip_bfloat16* Whb = (__hip_bfloat16*)d_ws;
    __hip_bfloat16* Mt  = Whb + (size_t)N_*T_*P_*V_;
    float* Eihi = (float*)(Mt + (size_t)N_*T_*V_*V_);   // 16*32*64
    float* Eihj = Eihi + (size_t)N_*H_*V_;
    float* adjn = Eihj + (size_t)N_*H_*V_;
    __hip_bfloat16* Bfrag = (__hip_bfloat16*)(adjn + V_*V_);

    // Xt scratch (37.9MB, h+w padded) lives in d_out; out_k overwrites it.
    __hip_bfloat16* Xt = (__hip_bfloat16*)d_out;

    tr2_k  <<<N_*34*4 + 1, 256, 0, stream>>>(X, Xt, CW, Bm, Bfrag, adjn);
    conv_k <<<2048,        256, 0, stream>>>(Xt, Bfrag, CB, av, Whb, Eihi, Eihj);
    att_m_k<<<N_*V_,       256, 0, stream>>>(Eihi, Eihj, adjn, Mt);
    out_k  <<<N_*T_*8,     256, 0, stream>>>(Whb, Mt, outp);
}